// Round 9
// baseline (465.331 us; speedup 1.0000x reference)
//
#include <hip/hip_runtime.h>
#include <hip/hip_bf16.h>

#define B_SZ   4096
#define NT     12          // tiles (node-pairs) per persistent block; 512 blocks * 12 = 6144

typedef short bf16x8 __attribute__((ext_vector_type(8)));
typedef short bf16x4 __attribute__((ext_vector_type(4)));
typedef float f32x4  __attribute__((ext_vector_type(4)));

__device__ __forceinline__ short f2bf(float f) {
    __hip_bfloat16 h = __float2bfloat16(f);
    return *reinterpret_cast<short*>(&h);
}
__device__ __forceinline__ float bf2f(unsigned int u16) {
    unsigned int x = u16 << 16;
    float f;
    __builtin_memcpy(&f, &x, 4);
    return f;
}
__device__ __forceinline__ float fsig(float x) {
    return __builtin_amdgcn_rcpf(1.0f + __expf(-x));
}
__device__ __forceinline__ float ftanhf(float x) {
    return 1.0f - 2.0f * __builtin_amdgcn_rcpf(__expf(2.0f * x) + 1.0f);
}
// XOR swizzle for row-major [64][256] bf16 tile (512 B rows)
__device__ __forceinline__ int swz(int row, int cbyte) {
    return row * 512 + (cbyte ^ ((row & 7) << 4));
}
// async global->LDS, 16B per lane; lds ptr must be wave-uniform base
__device__ __forceinline__ void gld16(const float* g, float* l) {
    __builtin_amdgcn_global_load_lds(
        (const __attribute__((address_space(1))) void*)g,
        (__attribute__((address_space(3))) void*)l,
        16, 0, 0);
}

// ---------------------------------------------------------------------------
// Kernel 0: weights -> fragment-major bf16 layout wfrag[g][ks][j][kh][8]
__global__ void prep_kernel(const float* __restrict__ wih, const float* __restrict__ whh,
                            short* __restrict__ wfrag) {
    int idx = blockIdx.x * 256 + threadIdx.x;     // 3*8*128*4*8 = 98304
    int i   = idx & 7;
    int kh  = (idx >> 3) & 3;
    int j   = (idx >> 5) & 127;
    int gks = idx >> 12;                          // g*8+ks
    int g   = gks >> 3, ks = gks & 7;
    int k   = ks * 32 + kh * 8 + i;
    int r   = g * 128 + j;
    float v = (k < 128) ? wih[r * 128 + k] : whh[r * 128 + (k - 128)];
    wfrag[idx] = f2bf(v);
}

// ---------------------------------------------------------------------------
// Kernel 1: persistent pipelined fused GRU. Block = 8 waves (512 thr),
// NT=12 tiles of 64 rows (2 nodes). Per iteration:
//   issue async global->LDS loads for tile t+1 (e_feat gather + hidden)
//   GEMM+epilogue on tile t (bf16 sT, verbatim round-3 math)
//   barrier (drains vmcnt) ; convert f32 LDS -> bf16 sT ; barrier
// Each lane converts exactly the 16B it loaded (lane-linear, conflict-free).
__global__ __launch_bounds__(512, 4) void gru_agg_kernel(
    const int*   __restrict__ ngh_id,
    const int*   __restrict__ e_idx,
    const float* __restrict__ ngh_ts,
    const float* __restrict__ hidden_store,
    const float* __restrict__ e_feat,
    const float* __restrict__ basis_freq,
    const float* __restrict__ phase,
    const float* __restrict__ cut_time,
    const short* __restrict__ wfrag,
    const float* __restrict__ b_ih,
    const float* __restrict__ b_hh,
    float*       __restrict__ agg)
{
    __shared__ float sE[4096];                    // 16KB f32 e_feat stage: wave w, chunk j at (w*2+j)*256
    __shared__ float sH8[8192];                   // 32KB f32 hidden stage: wave w, chunk k at (w*4+k)*256
    __shared__ __align__(16) char sT[32768];      // 32KB bf16 [64 rows][256 cols] swizzled

    const int tid  = threadIdx.x;
    const int lane = tid & 63;
    const int wv   = tid >> 6;
    const int l15  = lane & 15;
    const int kh   = lane >> 4;
    const int jc   = (wv << 4) + l15;

    const int tsrow = tid >> 3;                   // ts-convert row (0..63)
    const int tscol = (tid & 7) * 8;              // ts-convert col base

    // hoisted biases (same address every tile)
    const float brz = b_ih[jc] + b_hh[jc];
    const float bzz = b_ih[128 + jc] + b_hh[128 + jc];
    const float bin = b_ih[256 + jc];
    const float bhn = b_hh[256 + jc];

    const int tile0 = blockIdx.x * NT;
    const int erow  = wv * 8 + (lane >> 4);       // e_idx fetch rows

    // ---------- prologue: stage tile 0 ----------
    float tsr  = ngh_ts[(size_t)tile0 * 64 + tsrow];
    float ctr  = cut_time[(tile0 * 2 + (tsrow >> 5)) & (B_SZ - 1)];
    int   ngid = ngh_id[(size_t)tile0 * 64 + lane];
    int iA = e_idx[(size_t)tile0 * 64 + erow];
    int iB = e_idx[(size_t)tile0 * 64 + erow + 4];
    // issue tile0 loads
    gld16(e_feat + (size_t)iA * 64 + l15 * 4, &sE[(wv * 2 + 0) * 256]);
    gld16(e_feat + (size_t)iB * 64 + l15 * 4, &sE[(wv * 2 + 1) * 256]);
    #pragma unroll
    for (int k = 0; k < 4; ++k)
        gld16(hidden_store + (size_t)(tile0 * 64 + wv * 8 + k * 2 + (lane >> 5)) * 128 + (lane & 31) * 4,
              &sH8[(wv * 4 + k) * 256]);
    // idx for tile 1
    int cA = e_idx[(size_t)(tile0 + 1) * 64 + erow];
    int cB = e_idx[(size_t)(tile0 + 1) * 64 + erow + 4];

    __syncthreads();                              // drains vmcnt: tile0 f32 data in LDS

    // ---------- convert tile 0 ----------
    {
        #pragma unroll
        for (int j = 0; j < 2; ++j) {
            float4 v = *reinterpret_cast<const float4*>(&sE[(wv * 2 + j) * 256 + lane * 4]);
            int row = wv * 8 + j * 4 + (lane >> 4);
            bf16x4 o = { f2bf(v.x), f2bf(v.y), f2bf(v.z), f2bf(v.w) };
            *reinterpret_cast<bf16x4*>(&sT[swz(row, l15 * 8)]) = o;
        }
        #pragma unroll
        for (int k = 0; k < 4; ++k) {
            float4 v = *reinterpret_cast<const float4*>(&sH8[(wv * 4 + k) * 256 + lane * 4]);
            int row = wv * 8 + k * 2 + (lane >> 5);
            bf16x4 o = { f2bf(v.x), f2bf(v.y), f2bf(v.z), f2bf(v.w) };
            *reinterpret_cast<bf16x4*>(&sT[swz(row, 256 + (lane & 31) * 8)]) = o;
        }
        const float dt = ctr - tsr;
        union { short s[8]; bf16x8 w; } u;
        #pragma unroll
        for (int i = 0; i < 8; ++i)
            u.s[i] = f2bf(__cosf(dt * basis_freq[tscol + i] + phase[tscol + i]));
        *reinterpret_cast<bf16x8*>(&sT[swz(tsrow, 128 + (tid & 7) * 16)]) = u.w;
    }
    unsigned long long mb = __ballot(ngid != 0);
    int c0n = __popcll(mb & 0xFFFFFFFFull);
    int c1n = __popcll(mb >> 32);
    float inv0 = 1.0f / (float)(c0n > 1 ? c0n : 1);
    float inv1 = 1.0f / (float)(c1n > 1 ? c1n : 1);
    __syncthreads();                              // sT(0) visible to all

    // ---------- main loop ----------
    #pragma unroll 1
    for (int t = 0; t < NT; ++t) {
        const int tt = tile0 + t;
        float n_tsr = 0.f, n_ctr = 0.f;
        int   n_ngid = 0;
        if (t + 1 < NT) {
            // issue tile t+1 loads (async; land during GEMM below)
            gld16(e_feat + (size_t)cA * 64 + l15 * 4, &sE[(wv * 2 + 0) * 256]);
            gld16(e_feat + (size_t)cB * 64 + l15 * 4, &sE[(wv * 2 + 1) * 256]);
            #pragma unroll
            for (int k = 0; k < 4; ++k)
                gld16(hidden_store + (size_t)((tt + 1) * 64 + wv * 8 + k * 2 + (lane >> 5)) * 128 + (lane & 31) * 4,
                      &sH8[(wv * 4 + k) * 256]);
            n_tsr  = ngh_ts[(size_t)(tt + 1) * 64 + tsrow];
            n_ctr  = cut_time[((tt + 1) * 2 + (tsrow >> 5)) & (B_SZ - 1)];
            n_ngid = ngh_id[(size_t)(tt + 1) * 64 + lane];
            const int t2 = (t + 2 < NT) ? (tt + 2) : (tile0 + NT - 1);
            cA = e_idx[(size_t)t2 * 64 + erow];
            cB = e_idx[(size_t)t2 * 64 + erow + 4];
        }

        // ---- GEMM on tile t (verbatim round-3 math) ----
        f32x4 ar[4], az[4], axn[4], ahn[4];
        #pragma unroll
        for (int mf = 0; mf < 4; ++mf) {
            ar[mf]  = (f32x4){0.f, 0.f, 0.f, 0.f};
            az[mf]  = (f32x4){0.f, 0.f, 0.f, 0.f};
            axn[mf] = (f32x4){0.f, 0.f, 0.f, 0.f};
            ahn[mf] = (f32x4){0.f, 0.f, 0.f, 0.f};
        }
        #pragma unroll
        for (int ks = 0; ks < 8; ++ks) {
            bf16x8 a[4];
            #pragma unroll
            for (int mf = 0; mf < 4; ++mf)
                a[mf] = *reinterpret_cast<const bf16x8*>(&sT[swz(mf * 16 + l15, ks * 64 + kh * 16)]);
            bf16x8 br = *reinterpret_cast<const bf16x8*>(wfrag + (((((0 * 8 + ks) * 128 + jc) << 2) + kh) << 3));
            bf16x8 bz = *reinterpret_cast<const bf16x8*>(wfrag + (((((1 * 8 + ks) * 128 + jc) << 2) + kh) << 3));
            bf16x8 bn = *reinterpret_cast<const bf16x8*>(wfrag + (((((2 * 8 + ks) * 128 + jc) << 2) + kh) << 3));
            #pragma unroll
            for (int mf = 0; mf < 4; ++mf)
                ar[mf] = __builtin_amdgcn_mfma_f32_16x16x32_bf16(a[mf], br, ar[mf], 0, 0, 0);
            #pragma unroll
            for (int mf = 0; mf < 4; ++mf)
                az[mf] = __builtin_amdgcn_mfma_f32_16x16x32_bf16(a[mf], bz, az[mf], 0, 0, 0);
            if (ks < 4) {
                #pragma unroll
                for (int mf = 0; mf < 4; ++mf)
                    axn[mf] = __builtin_amdgcn_mfma_f32_16x16x32_bf16(a[mf], bn, axn[mf], 0, 0, 0);
            } else {
                #pragma unroll
                for (int mf = 0; mf < 4; ++mf)
                    ahn[mf] = __builtin_amdgcn_mfma_f32_16x16x32_bf16(a[mf], bn, ahn[mf], 0, 0, 0);
            }
        }

        // ---- epilogue ----
        float s0 = 0.f, s1 = 0.f;
        #pragma unroll
        for (int mf = 0; mf < 4; ++mf) {
            #pragma unroll
            for (int i = 0; i < 4; ++i) {
                const int row = mf * 16 + kh * 4 + i;
                const float rr = fsig(ar[mf][i] + brz);
                const float zz = fsig(az[mf][i] + bzz);
                const float nn = ftanhf(axn[mf][i] + bin + rr * (ahn[mf][i] + bhn));
                const float hc = bf2f(*reinterpret_cast<const unsigned short*>(&sT[swz(row, 256 + jc * 2)]));
                const float m  = (float)((mb >> row) & 1ull);
                const float hv = ((1.0f - zz) * nn + zz * hc) * m;
                if (mf < 2) s0 += hv; else s1 += hv;
            }
        }
        s0 += __shfl_xor(s0, 16, 64);
        s0 += __shfl_xor(s0, 32, 64);
        s1 += __shfl_xor(s1, 16, 64);
        s1 += __shfl_xor(s1, 32, 64);
        if (lane < 16) {
            agg[(size_t)(tt * 2 + 0) * 128 + jc] = s0 * inv0;
            agg[(size_t)(tt * 2 + 1) * 128 + jc] = s1 * inv1;
        }

        // ---- convert tile t+1 ----
        if (t + 1 < NT) {
            __syncthreads();                      // sT free; vmcnt drained (t+1 f32 data landed)
            #pragma unroll
            for (int j = 0; j < 2; ++j) {
                float4 v = *reinterpret_cast<const float4*>(&sE[(wv * 2 + j) * 256 + lane * 4]);
                int row = wv * 8 + j * 4 + (lane >> 4);
                bf16x4 o = { f2bf(v.x), f2bf(v.y), f2bf(v.z), f2bf(v.w) };
                *reinterpret_cast<bf16x4*>(&sT[swz(row, l15 * 8)]) = o;
            }
            #pragma unroll
            for (int k = 0; k < 4; ++k) {
                float4 v = *reinterpret_cast<const float4*>(&sH8[(wv * 4 + k) * 256 + lane * 4]);
                int row = wv * 8 + k * 2 + (lane >> 5);
                bf16x4 o = { f2bf(v.x), f2bf(v.y), f2bf(v.z), f2bf(v.w) };
                *reinterpret_cast<bf16x4*>(&sT[swz(row, 256 + (lane & 31) * 8)]) = o;
            }
            const float dt = n_ctr - n_tsr;
            union { short s[8]; bf16x8 w; } u;
            #pragma unroll
            for (int i = 0; i < 8; ++i)
                u.s[i] = f2bf(__cosf(dt * basis_freq[tscol + i] + phase[tscol + i]));
            *reinterpret_cast<bf16x8*>(&sT[swz(tsrow, 128 + (tid & 7) * 16)]) = u.w;

            mb  = __ballot(n_ngid != 0);
            c0n = __popcll(mb & 0xFFFFFFFFull);
            c1n = __popcll(mb >> 32);
            inv0 = 1.0f / (float)(c0n > 1 ? c0n : 1);
            inv1 = 1.0f / (float)(c1n > 1 ? c1n : 1);
            __syncthreads();                      // sT(t+1) visible
        }
    }
}

// ---------------------------------------------------------------------------
// Kernel 2: emb = relu([node_raw, agg] @ W_out^T + b_out); 16 nodes/block
__global__ __launch_bounds__(256) void emb_kernel(
    const int*   __restrict__ src_ids, const int* __restrict__ tgt_ids,
    const int*   __restrict__ bad_ids, const float* __restrict__ n_feat,
    const float* __restrict__ W_out,   const float* __restrict__ b_out,
    const float* __restrict__ agg,     float* __restrict__ emb)
{
    __shared__ float sv[16][192];
    const int base = blockIdx.x * 16;
    const int j  = threadIdx.x & 63;
    const int ng = threadIdx.x >> 6;
    #pragma unroll
    for (int n0 = 0; n0 < 4; ++n0) {
        const int n = ng * 4 + n0;
        const int node = base + n;
        int id;
        if (node < B_SZ)          id = src_ids[node];
        else if (node < 2 * B_SZ) id = tgt_ids[node - B_SZ];
        else                      id = bad_ids[node - 2 * B_SZ];
        sv[n][j]       = n_feat[(size_t)id * 64 + j];
        sv[n][64 + j]  = agg[(size_t)node * 128 + j];
        sv[n][128 + j] = agg[(size_t)node * 128 + 64 + j];
    }
    __syncthreads();
    float acc[4];
    const float bj = b_out[j];
    #pragma unroll
    for (int n0 = 0; n0 < 4; ++n0) acc[n0] = bj;
    const float4* wr = reinterpret_cast<const float4*>(W_out + j * 192);
    #pragma unroll 4
    for (int c = 0; c < 48; ++c) {
        float4 w = wr[c];
        #pragma unroll
        for (int n0 = 0; n0 < 4; ++n0) {
            const float* s = &sv[ng * 4 + n0][c * 4];
            acc[n0] += w.x * s[0] + w.y * s[1] + w.z * s[2] + w.w * s[3];
        }
    }
    #pragma unroll
    for (int n0 = 0; n0 < 4; ++n0)
        emb[(size_t)(base + ng * 4 + n0) * 64 + j] = fmaxf(acc[n0], 0.0f);
}

// ---------------------------------------------------------------------------
// Kernel 3: merge MLP; 16 pairs/block
__global__ __launch_bounds__(256) void merge_kernel(
    const float* __restrict__ emb,  const float* __restrict__ fc1_w,
    const float* __restrict__ fc1_b, const float* __restrict__ fc2_w,
    const float* __restrict__ fc2_b, float* __restrict__ out)
{
    __shared__ float se[16][192];
    const int base = blockIdx.x * 16;
    const int j  = threadIdx.x & 63;
    const int ng = threadIdx.x >> 6;
    #pragma unroll
    for (int p0 = 0; p0 < 4; ++p0) {
        const int p = ng * 4 + p0;
        const int i = base + p;
        se[p][j]       = emb[(size_t)i * 64 + j];
        se[p][64 + j]  = emb[(size_t)(B_SZ + i) * 64 + j];
        se[p][128 + j] = emb[(size_t)(2 * B_SZ + i) * 64 + j];
    }
    __syncthreads();
    const float4* w1 = reinterpret_cast<const float4*>(fc1_w + j * 128);
    float sp[4] = {0, 0, 0, 0}, tp[4] = {0, 0, 0, 0}, bp[4] = {0, 0, 0, 0};
    #pragma unroll 4
    for (int c = 0; c < 16; ++c) {
        float4 wa = w1[c];
        float4 wb = w1[16 + c];
        #pragma unroll
        for (int p0 = 0; p0 < 4; ++p0) {
            const float* s = se[ng * 4 + p0];
            const float* sa = &s[c * 4];
            sp[p0] += wa.x * sa[0] + wa.y * sa[1] + wa.z * sa[2] + wa.w * sa[3];
            const float* st = &s[64 + c * 4];
            tp[p0] += wb.x * st[0] + wb.y * st[1] + wb.z * st[2] + wb.w * st[3];
            const float* sb = &s[128 + c * 4];
            bp[p0] += wb.x * sb[0] + wb.y * sb[1] + wb.z * sb[2] + wb.w * sb[3];
        }
    }
    const float b1 = fc1_b[j];
    const float w2 = fc2_w[j];
    #pragma unroll
    for (int p0 = 0; p0 < 4; ++p0) {
        float p = fmaxf(b1 + sp[p0] + tp[p0], 0.f) * w2;
        float n = fmaxf(b1 + sp[p0] + bp[p0], 0.f) * w2;
        #pragma unroll
        for (int m = 32; m >= 1; m >>= 1) {
            p += __shfl_xor(p, m, 64);
            n += __shfl_xor(n, m, 64);
        }
        if (j == 0) {
            const int i = base + ng * 4 + p0;
            out[2 * i]     = p + fc2_b[0];
            out[2 * i + 1] = n + fc2_b[0];
        }
    }
}

// ---------------------------------------------------------------------------
extern "C" void kernel_launch(void* const* d_in, const int* in_sizes, int n_in,
                              void* d_out, int out_size, void* d_ws, size_t ws_size,
                              hipStream_t stream) {
    const int*   src_ids  = (const int*)  d_in[0];
    const int*   tgt_ids  = (const int*)  d_in[1];
    const int*   bad_ids  = (const int*)  d_in[2];
    const float* cut_time = (const float*)d_in[3];
    const int*   ngh_id   = (const int*)  d_in[4];
    const int*   e_idx    = (const int*)  d_in[5];
    const float* ngh_ts   = (const float*)d_in[6];
    const float* hidden   = (const float*)d_in[7];
    const float* n_feat   = (const float*)d_in[8];
    const float* e_feat   = (const float*)d_in[9];
    const float* basis    = (const float*)d_in[10];
    const float* phase    = (const float*)d_in[11];
    const float* W_ih     = (const float*)d_in[12];
    const float* W_hh     = (const float*)d_in[13];
    const float* b_ih     = (const float*)d_in[14];
    const float* b_hh     = (const float*)d_in[15];
    const float* W_out    = (const float*)d_in[16];
    const float* b_out    = (const float*)d_in[17];
    const float* fc1_w    = (const float*)d_in[18];
    const float* fc1_b    = (const float*)d_in[19];
    const float* fc2_w    = (const float*)d_in[20];
    const float* fc2_b    = (const float*)d_in[21];

    char* ws = (char*)d_ws;
    short* wfrag = (short*)(ws);                       // 98304*2 = 196608 B
    float* agg   = (float*)(ws + 196608);              // 12288*128*4 = 6291456 B
    float* emb   = (float*)(ws + 196608 + 6291456);    // 12288*64*4  = 3145728 B
    float* out   = (float*)d_out;

    hipLaunchKernelGGL(prep_kernel, dim3(384), dim3(256), 0, stream, W_ih, W_hh, wfrag);
    hipLaunchKernelGGL(gru_agg_kernel, dim3(512), dim3(512), 0, stream,
                       ngh_id, e_idx, ngh_ts, hidden, e_feat, basis, phase, cut_time,
                       wfrag, b_ih, b_hh, agg);
    hipLaunchKernelGGL(emb_kernel, dim3(768), dim3(256), 0, stream,
                       src_ids, tgt_ids, bad_ids, n_feat, W_out, b_out, agg, emb);
    hipLaunchKernelGGL(merge_kernel, dim3(256), dim3(256), 0, stream,
                       emb, fc1_w, fc1_b, fc2_w, fc2_b, out);
}

// Round 11
// 199.369 us; speedup vs baseline: 2.3340x; 2.3340x over previous
//
#include <hip/hip_runtime.h>
#include <hip/hip_bf16.h>

#define B_SZ   4096

typedef short bf16x8 __attribute__((ext_vector_type(8)));
typedef float f32x4  __attribute__((ext_vector_type(4)));

__device__ __forceinline__ short f2bf(float f) {
    __hip_bfloat16 h = __float2bfloat16(f);
    return *reinterpret_cast<short*>(&h);
}
__device__ __forceinline__ float bf2f(unsigned int u16) {
    unsigned int x = u16 << 16;
    float f;
    __builtin_memcpy(&f, &x, 4);
    return f;
}
__device__ __forceinline__ float fsig(float x) {
    return __builtin_amdgcn_rcpf(1.0f + __expf(-x));
}
__device__ __forceinline__ float ftanhf(float x) {
    return 1.0f - 2.0f * __builtin_amdgcn_rcpf(__expf(2.0f * x) + 1.0f);
}
// XOR swizzle for row-major [64][256] bf16 tile (512 B rows)
__device__ __forceinline__ int swz(int row, int cbyte) {
    return row * 512 + (cbyte ^ ((row & 7) << 4));
}

// ---------------------------------------------------------------------------
// Kernel 0: weights -> fragment-major bf16 layout wfrag[g][ks][j][kh][8]
__global__ void prep_kernel(const float* __restrict__ wih, const float* __restrict__ whh,
                            short* __restrict__ wfrag) {
    int idx = blockIdx.x * 256 + threadIdx.x;     // 3*8*128*4*8 = 98304
    int i   = idx & 7;
    int kh  = (idx >> 3) & 3;
    int j   = (idx >> 5) & 127;
    int gks = idx >> 12;                          // g*8+ks
    int g   = gks >> 3, ks = gks & 7;
    int k   = ks * 32 + kh * 8 + i;
    int r   = g * 128 + j;
    float v = (k < 128) ? wih[r * 128 + k] : whh[r * 128 + (k - 128)];
    wfrag[idx] = f2bf(v);
}

// ---------------------------------------------------------------------------
// Kernel 1: fused feature-build + merged GRU GEMM (K=256) + masked mean.
// Byte-identical to the verified round-3 kernel EXCEPT: B-fragment loads are
// software-rotated 1 kstep ahead, with ks=0's loads issued BEFORE the barrier
// (weights don't depend on staging -> latency hides under staging drain).
__global__ __launch_bounds__(512, 4) void gru_agg_kernel(
    const int*   __restrict__ ngh_id,
    const int*   __restrict__ e_idx,
    const float* __restrict__ ngh_ts,
    const float* __restrict__ hidden_store,
    const float* __restrict__ e_feat,
    const float* __restrict__ basis_freq,
    const float* __restrict__ phase,
    const float* __restrict__ cut_time,
    const short* __restrict__ wfrag,
    const float* __restrict__ b_ih,
    const float* __restrict__ b_hh,
    float*       __restrict__ agg)
{
    __shared__ __align__(16) char sT[64 * 512];   // [64 rows][256 bf16 cols] swizzled
    __shared__ float sMask[64];
    __shared__ float sInv[2];

    const int bid  = blockIdx.x;
    const int tid  = threadIdx.x;
    const int lane = tid & 63;
    const int wv   = tid >> 6;

    // GEMM lane geometry (needed early for the pre-barrier weight prefetch)
    const int l15 = lane & 15;
    const int kh  = lane >> 4;
    const int jc  = (wv << 4) + l15;
    const short* wbase = wfrag + ((((size_t)jc << 2) + kh) << 3);
    // fragment address for gate g, kstep ks:
    //   wbase + (g*8 + ks) * 4096   (elements)

    // ---- wave-specialized staging (verbatim round-3) ----
    if (wv < 2) {                                 // e_emb: wave0 cols 0-31, wave1 32-63
        const int row  = lane;
        const int flat = bid * 64 + row;
        const int e    = e_idx[flat];
        const float4* src = reinterpret_cast<const float4*>(e_feat + (size_t)e * 64 + wv * 32);
        float v[32];
        #pragma unroll
        for (int t = 0; t < 8; ++t) *reinterpret_cast<float4*>(&v[t * 4]) = src[t];
        union { bf16x8 w[4]; short s[32]; } u;
        #pragma unroll
        for (int i = 0; i < 32; ++i) u.s[i] = f2bf(v[i]);
        const int cb = wv * 64;
        #pragma unroll
        for (int t = 0; t < 4; ++t)
            *reinterpret_cast<bf16x8*>(&sT[swz(row, cb + t * 16)]) = u.w[t];
    } else if (wv < 4) {                          // ts_emb + (wave2) mask/counts
        const int row  = lane;
        const int flat = bid * 64 + row;
        if (wv == 2) {
            const int nid = ngh_id[flat];
            sMask[row] = (nid != 0) ? 1.0f : 0.0f;
            unsigned long long mb = __ballot(nid != 0);
            if (lane == 0) {
                int c0n = __popcll(mb & 0xFFFFFFFFull);
                int c1n = __popcll(mb >> 32);
                sInv[0] = 1.0f / (float)(c0n > 1 ? c0n : 1);
                sInv[1] = 1.0f / (float)(c1n > 1 ? c1n : 1);
            }
        }
        const int rnode = bid * 2 + (row >> 5);
        const float dt  = cut_time[rnode & (B_SZ - 1)] - ngh_ts[flat];
        const int f0 = (wv - 2) * 32;
        float v[32];
        #pragma unroll
        for (int i = 0; i < 32; ++i)
            v[i] = __cosf(dt * basis_freq[f0 + i] + phase[f0 + i]);
        union { bf16x8 w[4]; short s[32]; } u;
        #pragma unroll
        for (int i = 0; i < 32; ++i) u.s[i] = f2bf(v[i]);
        const int cb = 128 + f0 * 2;
        #pragma unroll
        for (int t = 0; t < 4; ++t)
            *reinterpret_cast<bf16x8*>(&sT[swz(row, cb + t * 16)]) = u.w[t];
    } else {                                      // hidden: wave 4+hw rows hw*16..+16
        const int hw   = wv - 4;
        const int row  = hw * 16 + (lane >> 2);
        const int flat = bid * 64 + row;
        const int c0   = (lane & 3) * 32;
        const float4* src = reinterpret_cast<const float4*>(hidden_store + (size_t)flat * 128 + c0);
        float v[32];
        #pragma unroll
        for (int t = 0; t < 8; ++t) *reinterpret_cast<float4*>(&v[t * 4]) = src[t];
        union { bf16x8 w[4]; short s[32]; } u;
        #pragma unroll
        for (int i = 0; i < 32; ++i) u.s[i] = f2bf(v[i]);
        const int cb = 256 + c0 * 2;
        #pragma unroll
        for (int t = 0; t < 4; ++t)
            *reinterpret_cast<bf16x8*>(&sT[swz(row, cb + t * 16)]) = u.w[t];
    }

    // ---- pre-barrier weight prefetch for ks = 0 (independent of staging) ----
    bf16x8 br_p = *reinterpret_cast<const bf16x8*>(wbase + (0 * 8 + 0) * 4096);
    bf16x8 bz_p = *reinterpret_cast<const bf16x8*>(wbase + (1 * 8 + 0) * 4096);
    bf16x8 bn_p = *reinterpret_cast<const bf16x8*>(wbase + (2 * 8 + 0) * 4096);

    __syncthreads();

    // ---- K-loop: K=256 merged GEMM, B-loads rotated 1 kstep ahead ----
    f32x4 ar[4], az[4], axn[4], ahn[4];
    #pragma unroll
    for (int mf = 0; mf < 4; ++mf) {
        ar[mf]  = (f32x4){0.f, 0.f, 0.f, 0.f};
        az[mf]  = (f32x4){0.f, 0.f, 0.f, 0.f};
        axn[mf] = (f32x4){0.f, 0.f, 0.f, 0.f};
        ahn[mf] = (f32x4){0.f, 0.f, 0.f, 0.f};
    }

    #pragma unroll
    for (int ks = 0; ks < 8; ++ks) {
        bf16x8 br = br_p, bz = bz_p, bn = bn_p;
        if (ks < 7) {                             // issue next-kstep loads first
            br_p = *reinterpret_cast<const bf16x8*>(wbase + (0 * 8 + ks + 1) * 4096);
            bz_p = *reinterpret_cast<const bf16x8*>(wbase + (1 * 8 + ks + 1) * 4096);
            bn_p = *reinterpret_cast<const bf16x8*>(wbase + (2 * 8 + ks + 1) * 4096);
        }
        bf16x8 a[4];
        #pragma unroll
        for (int mf = 0; mf < 4; ++mf)
            a[mf] = *reinterpret_cast<const bf16x8*>(&sT[swz(mf * 16 + l15, ks * 64 + kh * 16)]);
        #pragma unroll
        for (int mf = 0; mf < 4; ++mf)
            ar[mf] = __builtin_amdgcn_mfma_f32_16x16x32_bf16(a[mf], br, ar[mf], 0, 0, 0);
        #pragma unroll
        for (int mf = 0; mf < 4; ++mf)
            az[mf] = __builtin_amdgcn_mfma_f32_16x16x32_bf16(a[mf], bz, az[mf], 0, 0, 0);
        if (ks < 4) {
            #pragma unroll
            for (int mf = 0; mf < 4; ++mf)
                axn[mf] = __builtin_amdgcn_mfma_f32_16x16x32_bf16(a[mf], bn, axn[mf], 0, 0, 0);
        } else {
            #pragma unroll
            for (int mf = 0; mf < 4; ++mf)
                ahn[mf] = __builtin_amdgcn_mfma_f32_16x16x32_bf16(a[mf], bn, ahn[mf], 0, 0, 0);
        }
    }

    // ---- epilogue: gates, h_new, masked sum over K, mean (verbatim r3) ----
    const float brz = b_ih[jc] + b_hh[jc];
    const float bzz = b_ih[128 + jc] + b_hh[128 + jc];
    const float bin = b_ih[256 + jc];
    const float bhn = b_hh[256 + jc];

    float s0 = 0.f, s1 = 0.f;
    #pragma unroll
    for (int mf = 0; mf < 4; ++mf) {
        #pragma unroll
        for (int i = 0; i < 4; ++i) {
            const int row = mf * 16 + kh * 4 + i;     // C/D: col=l15, row=kh*4+i
            const float rr = fsig(ar[mf][i] + brz);
            const float zz = fsig(az[mf][i] + bzz);
            const float nn = ftanhf(axn[mf][i] + bin + rr * (ahn[mf][i] + bhn));
            const float hc = bf2f(*reinterpret_cast<const unsigned short*>(&sT[swz(row, 256 + jc * 2)]));
            const float hv = ((1.0f - zz) * nn + zz * hc) * sMask[row];
            if (mf < 2) s0 += hv; else s1 += hv;
        }
    }
    s0 += __shfl_xor(s0, 16, 64);
    s0 += __shfl_xor(s0, 32, 64);
    s1 += __shfl_xor(s1, 16, 64);
    s1 += __shfl_xor(s1, 32, 64);
    if (lane < 16) {
        agg[(bid * 2 + 0) * 128 + jc] = s0 * sInv[0];
        agg[(bid * 2 + 1) * 128 + jc] = s1 * sInv[1];
    }
}

// ---------------------------------------------------------------------------
// Kernel 2: emb = relu([node_raw, agg] @ W_out^T + b_out); 16 nodes/block
__global__ __launch_bounds__(256) void emb_kernel(
    const int*   __restrict__ src_ids, const int* __restrict__ tgt_ids,
    const int*   __restrict__ bad_ids, const float* __restrict__ n_feat,
    const float* __restrict__ W_out,   const float* __restrict__ b_out,
    const float* __restrict__ agg,     float* __restrict__ emb)
{
    __shared__ float sv[16][192];
    const int base = blockIdx.x * 16;
    const int j  = threadIdx.x & 63;
    const int ng = threadIdx.x >> 6;
    #pragma unroll
    for (int n0 = 0; n0 < 4; ++n0) {
        const int n = ng * 4 + n0;
        const int node = base + n;
        int id;
        if (node < B_SZ)          id = src_ids[node];
        else if (node < 2 * B_SZ) id = tgt_ids[node - B_SZ];
        else                      id = bad_ids[node - 2 * B_SZ];
        sv[n][j]       = n_feat[(size_t)id * 64 + j];
        sv[n][64 + j]  = agg[(size_t)node * 128 + j];
        sv[n][128 + j] = agg[(size_t)node * 128 + 64 + j];
    }
    __syncthreads();
    float acc[4];
    const float bj = b_out[j];
    #pragma unroll
    for (int n0 = 0; n0 < 4; ++n0) acc[n0] = bj;
    const float4* wr = reinterpret_cast<const float4*>(W_out + j * 192);
    #pragma unroll 4
    for (int c = 0; c < 48; ++c) {
        float4 w = wr[c];
        #pragma unroll
        for (int n0 = 0; n0 < 4; ++n0) {
            const float* s = &sv[ng * 4 + n0][c * 4];
            acc[n0] += w.x * s[0] + w.y * s[1] + w.z * s[2] + w.w * s[3];
        }
    }
    #pragma unroll
    for (int n0 = 0; n0 < 4; ++n0)
        emb[(size_t)(base + ng * 4 + n0) * 64 + j] = fmaxf(acc[n0], 0.0f);
}

// ---------------------------------------------------------------------------
// Kernel 3: merge MLP; 16 pairs/block
__global__ __launch_bounds__(256) void merge_kernel(
    const float* __restrict__ emb,  const float* __restrict__ fc1_w,
    const float* __restrict__ fc1_b, const float* __restrict__ fc2_w,
    const float* __restrict__ fc2_b, float* __restrict__ out)
{
    __shared__ float se[16][192];
    const int base = blockIdx.x * 16;
    const int j  = threadIdx.x & 63;
    const int ng = threadIdx.x >> 6;
    #pragma unroll
    for (int p0 = 0; p0 < 4; ++p0) {
        const int p = ng * 4 + p0;
        const int i = base + p;
        se[p][j]       = emb[(size_t)i * 64 + j];
        se[p][64 + j]  = emb[(size_t)(B_SZ + i) * 64 + j];
        se[p][128 + j] = emb[(size_t)(2 * B_SZ + i) * 64 + j];
    }
    __syncthreads();
    const float4* w1 = reinterpret_cast<const float4*>(fc1_w + j * 128);
    float sp[4] = {0, 0, 0, 0}, tp[4] = {0, 0, 0, 0}, bp[4] = {0, 0, 0, 0};
    #pragma unroll 4
    for (int c = 0; c < 16; ++c) {
        float4 wa = w1[c];
        float4 wb = w1[16 + c];
        #pragma unroll
        for (int p0 = 0; p0 < 4; ++p0) {
            const float* s = se[ng * 4 + p0];
            const float* sa = &s[c * 4];
            sp[p0] += wa.x * sa[0] + wa.y * sa[1] + wa.z * sa[2] + wa.w * sa[3];
            const float* st = &s[64 + c * 4];
            tp[p0] += wb.x * st[0] + wb.y * st[1] + wb.z * st[2] + wb.w * st[3];
            const float* sb = &s[128 + c * 4];
            bp[p0] += wb.x * sb[0] + wb.y * sb[1] + wb.z * sb[2] + wb.w * sb[3];
        }
    }
    const float b1 = fc1_b[j];
    const float w2 = fc2_w[j];
    #pragma unroll
    for (int p0 = 0; p0 < 4; ++p0) {
        float p = fmaxf(b1 + sp[p0] + tp[p0], 0.f) * w2;
        float n = fmaxf(b1 + sp[p0] + bp[p0], 0.f) * w2;
        #pragma unroll
        for (int m = 32; m >= 1; m >>= 1) {
            p += __shfl_xor(p, m, 64);
            n += __shfl_xor(n, m, 64);
        }
        if (j == 0) {
            const int i = base + ng * 4 + p0;
            out[2 * i]     = p + fc2_b[0];
            out[2 * i + 1] = n + fc2_b[0];
        }
    }
}

// ---------------------------------------------------------------------------
extern "C" void kernel_launch(void* const* d_in, const int* in_sizes, int n_in,
                              void* d_out, int out_size, void* d_ws, size_t ws_size,
                              hipStream_t stream) {
    const int*   src_ids  = (const int*)  d_in[0];
    const int*   tgt_ids  = (const int*)  d_in[1];
    const int*   bad_ids  = (const int*)  d_in[2];
    const float* cut_time = (const float*)d_in[3];
    const int*   ngh_id   = (const int*)  d_in[4];
    const int*   e_idx    = (const int*)  d_in[5];
    const float* ngh_ts   = (const float*)d_in[6];
    const float* hidden   = (const float*)d_in[7];
    const float* n_feat   = (const float*)d_in[8];
    const float* e_feat   = (const float*)d_in[9];
    const float* basis    = (const float*)d_in[10];
    const float* phase    = (const float*)d_in[11];
    const float* W_ih     = (const float*)d_in[12];
    const float* W_hh     = (const float*)d_in[13];
    const float* b_ih     = (const float*)d_in[14];
    const float* b_hh     = (const float*)d_in[15];
    const float* W_out    = (const float*)d_in[16];
    const float* b_out    = (const float*)d_in[17];
    const float* fc1_w    = (const float*)d_in[18];
    const float* fc1_b    = (const float*)d_in[19];
    const float* fc2_w    = (const float*)d_in[20];
    const float* fc2_b    = (const float*)d_in[21];

    char* ws = (char*)d_ws;
    short* wfrag = (short*)(ws);                       // 98304*2 = 196608 B
    float* agg   = (float*)(ws + 196608);              // 12288*128*4 = 6291456 B
    float* emb   = (float*)(ws + 196608 + 6291456);    // 12288*64*4  = 3145728 B
    float* out   = (float*)d_out;

    hipLaunchKernelGGL(prep_kernel, dim3(384), dim3(256), 0, stream, W_ih, W_hh, wfrag);
    hipLaunchKernelGGL(gru_agg_kernel, dim3(6144), dim3(512), 0, stream,
                       ngh_id, e_idx, ngh_ts, hidden, e_feat, basis, phase, cut_time,
                       wfrag, b_ih, b_hh, agg);
    hipLaunchKernelGGL(emb_kernel, dim3(768), dim3(256), 0, stream,
                       src_ids, tgt_ids, bad_ids, n_feat, W_out, b_out, agg, emb);
    hipLaunchKernelGGL(merge_kernel, dim3(256), dim3(256), 0, stream,
                       emb, fc1_w, fc1_b, fc2_w, fc2_b, out);
}

// Round 12
// 181.767 us; speedup vs baseline: 2.5600x; 1.0968x over previous
//
#include <hip/hip_runtime.h>
#include <hip/hip_bf16.h>

#define B_SZ   4096

typedef short bf16x8 __attribute__((ext_vector_type(8)));
typedef float f32x4  __attribute__((ext_vector_type(4)));

__device__ __forceinline__ short f2bf(float f) {
    __hip_bfloat16 h = __float2bfloat16(f);
    return *reinterpret_cast<short*>(&h);
}
__device__ __forceinline__ float bf2f(unsigned int u16) {
    unsigned int x = u16 << 16;
    float f;
    __builtin_memcpy(&f, &x, 4);
    return f;
}
__device__ __forceinline__ float fsig(float x) {
    return __builtin_amdgcn_rcpf(1.0f + __expf(-x));
}
__device__ __forceinline__ float ftanhf(float x) {
    return 1.0f - 2.0f * __builtin_amdgcn_rcpf(__expf(2.0f * x) + 1.0f);
}
// XOR swizzle for row-major [64][256] bf16 tile (512 B rows)
__device__ __forceinline__ int swz(int row, int cbyte) {
    return row * 512 + (cbyte ^ ((row & 7) << 4));
}

// ---------------------------------------------------------------------------
// Kernel 0: weights -> fragment-major bf16 layout wfrag[g][ks][j][kh][8]
// so each wave's B-fragment load is one fully-coalesced 1KB burst.
__global__ void prep_kernel(const float* __restrict__ wih, const float* __restrict__ whh,
                            short* __restrict__ wfrag) {
    int idx = blockIdx.x * 256 + threadIdx.x;     // 3*8*128*4*8 = 98304
    int i   = idx & 7;
    int kh  = (idx >> 3) & 3;
    int j   = (idx >> 5) & 127;
    int gks = idx >> 12;                          // g*8+ks
    int g   = gks >> 3, ks = gks & 7;
    int k   = ks * 32 + kh * 8 + i;
    int r   = g * 128 + j;
    float v = (k < 128) ? wih[r * 128 + k] : whh[r * 128 + (k - 128)];
    wfrag[idx] = f2bf(v);
}

// ---------------------------------------------------------------------------
// Kernel 1: fused feature-build + merged GRU GEMM (K=256) + masked mean.
// Block = 2 nodes = 64 rows, 8 waves. Staging is WAVE-SPECIALIZED:
// waves 0-1: e_feat gather; waves 2-3: cos(ts) + mask; waves 4-7: hidden copy.
// This is the verified round-3 kernel (181.6 us bench): single-pass GEMM,
// scalar RNE f2bf, (512,4) = exactly at the 128-reg cliff with no spill.
// Measured walls: +regs in K-loop -> spill (r6/r7/r8/r10); smaller tile ->
// amortization loss (r5). Do not perturb without re-checking WRITE_SIZE.
__global__ __launch_bounds__(512, 4) void gru_agg_kernel(
    const int*   __restrict__ ngh_id,
    const int*   __restrict__ e_idx,
    const float* __restrict__ ngh_ts,
    const float* __restrict__ hidden_store,
    const float* __restrict__ e_feat,
    const float* __restrict__ basis_freq,
    const float* __restrict__ phase,
    const float* __restrict__ cut_time,
    const short* __restrict__ wfrag,
    const float* __restrict__ b_ih,
    const float* __restrict__ b_hh,
    float*       __restrict__ agg)
{
    __shared__ __align__(16) char sT[64 * 512];   // [64 rows][256 bf16 cols] swizzled
    __shared__ float sMask[64];
    __shared__ float sInv[2];

    const int bid  = blockIdx.x;
    const int tid  = threadIdx.x;
    const int lane = tid & 63;
    const int wv   = tid >> 6;

    // ---- wave-specialized staging ----
    if (wv < 2) {                                 // e_emb: wave0 cols 0-31, wave1 32-63
        const int row  = lane;
        const int flat = bid * 64 + row;
        const int e    = e_idx[flat];
        const float4* src = reinterpret_cast<const float4*>(e_feat + (size_t)e * 64 + wv * 32);
        float v[32];
        #pragma unroll
        for (int t = 0; t < 8; ++t) *reinterpret_cast<float4*>(&v[t * 4]) = src[t];
        union { bf16x8 w[4]; short s[32]; } u;
        #pragma unroll
        for (int i = 0; i < 32; ++i) u.s[i] = f2bf(v[i]);
        const int cb = wv * 64;
        #pragma unroll
        for (int t = 0; t < 4; ++t)
            *reinterpret_cast<bf16x8*>(&sT[swz(row, cb + t * 16)]) = u.w[t];
    } else if (wv < 4) {                          // ts_emb + (wave2) mask/counts
        const int row  = lane;
        const int flat = bid * 64 + row;
        if (wv == 2) {
            const int nid = ngh_id[flat];
            sMask[row] = (nid != 0) ? 1.0f : 0.0f;
            unsigned long long mb = __ballot(nid != 0);
            if (lane == 0) {
                int c0n = __popcll(mb & 0xFFFFFFFFull);
                int c1n = __popcll(mb >> 32);
                sInv[0] = 1.0f / (float)(c0n > 1 ? c0n : 1);
                sInv[1] = 1.0f / (float)(c1n > 1 ? c1n : 1);
            }
        }
        const int rnode = bid * 2 + (row >> 5);
        const float dt  = cut_time[rnode & (B_SZ - 1)] - ngh_ts[flat];
        const int f0 = (wv - 2) * 32;
        float v[32];
        #pragma unroll
        for (int i = 0; i < 32; ++i)
            v[i] = __cosf(dt * basis_freq[f0 + i] + phase[f0 + i]);
        union { bf16x8 w[4]; short s[32]; } u;
        #pragma unroll
        for (int i = 0; i < 32; ++i) u.s[i] = f2bf(v[i]);
        const int cb = 128 + f0 * 2;
        #pragma unroll
        for (int t = 0; t < 4; ++t)
            *reinterpret_cast<bf16x8*>(&sT[swz(row, cb + t * 16)]) = u.w[t];
    } else {                                      // hidden: wave 4+hw rows hw*16..+16
        const int hw   = wv - 4;
        const int row  = hw * 16 + (lane >> 2);
        const int flat = bid * 64 + row;
        const int c0   = (lane & 3) * 32;
        const float4* src = reinterpret_cast<const float4*>(hidden_store + (size_t)flat * 128 + c0);
        float v[32];
        #pragma unroll
        for (int t = 0; t < 8; ++t) *reinterpret_cast<float4*>(&v[t * 4]) = src[t];
        union { bf16x8 w[4]; short s[32]; } u;
        #pragma unroll
        for (int i = 0; i < 32; ++i) u.s[i] = f2bf(v[i]);
        const int cb = 256 + c0 * 2;
        #pragma unroll
        for (int t = 0; t < 4; ++t)
            *reinterpret_cast<bf16x8*>(&sT[swz(row, cb + t * 16)]) = u.w[t];
    }
    __syncthreads();

    // ---- K-loop: K=256 merged GEMM (single pass) ----
    const int l15 = lane & 15;
    const int kh  = lane >> 4;
    const int jc  = (wv << 4) + l15;

    f32x4 ar[4], az[4], axn[4], ahn[4];
    #pragma unroll
    for (int mf = 0; mf < 4; ++mf) {
        ar[mf]  = (f32x4){0.f, 0.f, 0.f, 0.f};
        az[mf]  = (f32x4){0.f, 0.f, 0.f, 0.f};
        axn[mf] = (f32x4){0.f, 0.f, 0.f, 0.f};
        ahn[mf] = (f32x4){0.f, 0.f, 0.f, 0.f};
    }

    #pragma unroll
    for (int ks = 0; ks < 8; ++ks) {
        bf16x8 a[4];
        #pragma unroll
        for (int mf = 0; mf < 4; ++mf)
            a[mf] = *reinterpret_cast<const bf16x8*>(&sT[swz(mf * 16 + l15, ks * 64 + kh * 16)]);
        bf16x8 br = *reinterpret_cast<const bf16x8*>(wfrag + (((((0 * 8 + ks) * 128 + jc) << 2) + kh) << 3));
        bf16x8 bz = *reinterpret_cast<const bf16x8*>(wfrag + (((((1 * 8 + ks) * 128 + jc) << 2) + kh) << 3));
        bf16x8 bn = *reinterpret_cast<const bf16x8*>(wfrag + (((((2 * 8 + ks) * 128 + jc) << 2) + kh) << 3));
        #pragma unroll
        for (int mf = 0; mf < 4; ++mf)
            ar[mf] = __builtin_amdgcn_mfma_f32_16x16x32_bf16(a[mf], br, ar[mf], 0, 0, 0);
        #pragma unroll
        for (int mf = 0; mf < 4; ++mf)
            az[mf] = __builtin_amdgcn_mfma_f32_16x16x32_bf16(a[mf], bz, az[mf], 0, 0, 0);
        if (ks < 4) {
            #pragma unroll
            for (int mf = 0; mf < 4; ++mf)
                axn[mf] = __builtin_amdgcn_mfma_f32_16x16x32_bf16(a[mf], bn, axn[mf], 0, 0, 0);
        } else {
            #pragma unroll
            for (int mf = 0; mf < 4; ++mf)
                ahn[mf] = __builtin_amdgcn_mfma_f32_16x16x32_bf16(a[mf], bn, ahn[mf], 0, 0, 0);
        }
    }

    // ---- epilogue: gates, h_new, masked sum over K, mean ----
    const float brz = b_ih[jc] + b_hh[jc];
    const float bzz = b_ih[128 + jc] + b_hh[128 + jc];
    const float bin = b_ih[256 + jc];
    const float bhn = b_hh[256 + jc];

    float s0 = 0.f, s1 = 0.f;
    #pragma unroll
    for (int mf = 0; mf < 4; ++mf) {
        #pragma unroll
        for (int i = 0; i < 4; ++i) {
            const int row = mf * 16 + kh * 4 + i;     // C/D: col=l15, row=kh*4+i
            const float rr = fsig(ar[mf][i] + brz);
            const float zz = fsig(az[mf][i] + bzz);
            const float nn = ftanhf(axn[mf][i] + bin + rr * (ahn[mf][i] + bhn));
            const float hc = bf2f(*reinterpret_cast<const unsigned short*>(&sT[swz(row, 256 + jc * 2)]));
            const float hv = ((1.0f - zz) * nn + zz * hc) * sMask[row];
            if (mf < 2) s0 += hv; else s1 += hv;
        }
    }
    s0 += __shfl_xor(s0, 16, 64);
    s0 += __shfl_xor(s0, 32, 64);
    s1 += __shfl_xor(s1, 16, 64);
    s1 += __shfl_xor(s1, 32, 64);
    if (lane < 16) {
        agg[(bid * 2 + 0) * 128 + jc] = s0 * sInv[0];
        agg[(bid * 2 + 1) * 128 + jc] = s1 * sInv[1];
    }
}

// ---------------------------------------------------------------------------
// Kernel 2: emb = relu([node_raw, agg] @ W_out^T + b_out); 16 nodes/block
__global__ __launch_bounds__(256) void emb_kernel(
    const int*   __restrict__ src_ids, const int* __restrict__ tgt_ids,
    const int*   __restrict__ bad_ids, const float* __restrict__ n_feat,
    const float* __restrict__ W_out,   const float* __restrict__ b_out,
    const float* __restrict__ agg,     float* __restrict__ emb)
{
    __shared__ float sv[16][192];
    const int base = blockIdx.x * 16;
    const int j  = threadIdx.x & 63;
    const int ng = threadIdx.x >> 6;
    #pragma unroll
    for (int n0 = 0; n0 < 4; ++n0) {
        const int n = ng * 4 + n0;
        const int node = base + n;
        int id;
        if (node < B_SZ)          id = src_ids[node];
        else if (node < 2 * B_SZ) id = tgt_ids[node - B_SZ];
        else                      id = bad_ids[node - 2 * B_SZ];
        sv[n][j]       = n_feat[(size_t)id * 64 + j];
        sv[n][64 + j]  = agg[(size_t)node * 128 + j];
        sv[n][128 + j] = agg[(size_t)node * 128 + 64 + j];
    }
    __syncthreads();
    float acc[4];
    const float bj = b_out[j];
    #pragma unroll
    for (int n0 = 0; n0 < 4; ++n0) acc[n0] = bj;
    const float4* wr = reinterpret_cast<const float4*>(W_out + j * 192);
    #pragma unroll 4
    for (int c = 0; c < 48; ++c) {
        float4 w = wr[c];
        #pragma unroll
        for (int n0 = 0; n0 < 4; ++n0) {
            const float* s = &sv[ng * 4 + n0][c * 4];
            acc[n0] += w.x * s[0] + w.y * s[1] + w.z * s[2] + w.w * s[3];
        }
    }
    #pragma unroll
    for (int n0 = 0; n0 < 4; ++n0)
        emb[(size_t)(base + ng * 4 + n0) * 64 + j] = fmaxf(acc[n0], 0.0f);
}

// ---------------------------------------------------------------------------
// Kernel 3: merge MLP; 16 pairs/block
__global__ __launch_bounds__(256) void merge_kernel(
    const float* __restrict__ emb,  const float* __restrict__ fc1_w,
    const float* __restrict__ fc1_b, const float* __restrict__ fc2_w,
    const float* __restrict__ fc2_b, float* __restrict__ out)
{
    __shared__ float se[16][192];
    const int base = blockIdx.x * 16;
    const int j  = threadIdx.x & 63;
    const int ng = threadIdx.x >> 6;
    #pragma unroll
    for (int p0 = 0; p0 < 4; ++p0) {
        const int p = ng * 4 + p0;
        const int i = base + p;
        se[p][j]       = emb[(size_t)i * 64 + j];
        se[p][64 + j]  = emb[(size_t)(B_SZ + i) * 64 + j];
        se[p][128 + j] = emb[(size_t)(2 * B_SZ + i) * 64 + j];
    }
    __syncthreads();
    const float4* w1 = reinterpret_cast<const float4*>(fc1_w + j * 128);
    float sp[4] = {0, 0, 0, 0}, tp[4] = {0, 0, 0, 0}, bp[4] = {0, 0, 0, 0};
    #pragma unroll 4
    for (int c = 0; c < 16; ++c) {
        float4 wa = w1[c];
        float4 wb = w1[16 + c];
        #pragma unroll
        for (int p0 = 0; p0 < 4; ++p0) {
            const float* s = se[ng * 4 + p0];
            const float* sa = &s[c * 4];
            sp[p0] += wa.x * sa[0] + wa.y * sa[1] + wa.z * sa[2] + wa.w * sa[3];
            const float* st = &s[64 + c * 4];
            tp[p0] += wb.x * st[0] + wb.y * st[1] + wb.z * st[2] + wb.w * st[3];
            const float* sb = &s[128 + c * 4];
            bp[p0] += wb.x * sb[0] + wb.y * sb[1] + wb.z * sb[2] + wb.w * sb[3];
        }
    }
    const float b1 = fc1_b[j];
    const float w2 = fc2_w[j];
    #pragma unroll
    for (int p0 = 0; p0 < 4; ++p0) {
        float p = fmaxf(b1 + sp[p0] + tp[p0], 0.f) * w2;
        float n = fmaxf(b1 + sp[p0] + bp[p0], 0.f) * w2;
        #pragma unroll
        for (int m = 32; m >= 1; m >>= 1) {
            p += __shfl_xor(p, m, 64);
            n += __shfl_xor(n, m, 64);
        }
        if (j == 0) {
            const int i = base + ng * 4 + p0;
            out[2 * i]     = p + fc2_b[0];
            out[2 * i + 1] = n + fc2_b[0];
        }
    }
}

// ---------------------------------------------------------------------------
extern "C" void kernel_launch(void* const* d_in, const int* in_sizes, int n_in,
                              void* d_out, int out_size, void* d_ws, size_t ws_size,
                              hipStream_t stream) {
    const int*   src_ids  = (const int*)  d_in[0];
    const int*   tgt_ids  = (const int*)  d_in[1];
    const int*   bad_ids  = (const int*)  d_in[2];
    const float* cut_time = (const float*)d_in[3];
    const int*   ngh_id   = (const int*)  d_in[4];
    const int*   e_idx    = (const int*)  d_in[5];
    const float* ngh_ts   = (const float*)d_in[6];
    const float* hidden   = (const float*)d_in[7];
    const float* n_feat   = (const float*)d_in[8];
    const float* e_feat   = (const float*)d_in[9];
    const float* basis    = (const float*)d_in[10];
    const float* phase    = (const float*)d_in[11];
    const float* W_ih     = (const float*)d_in[12];
    const float* W_hh     = (const float*)d_in[13];
    const float* b_ih     = (const float*)d_in[14];
    const float* b_hh     = (const float*)d_in[15];
    const float* W_out    = (const float*)d_in[16];
    const float* b_out    = (const float*)d_in[17];
    const float* fc1_w    = (const float*)d_in[18];
    const float* fc1_b    = (const float*)d_in[19];
    const float* fc2_w    = (const float*)d_in[20];
    const float* fc2_b    = (const float*)d_in[21];

    char* ws = (char*)d_ws;
    short* wfrag = (short*)(ws);                       // 98304*2 = 196608 B
    float* agg   = (float*)(ws + 196608);              // 12288*128*4 = 6291456 B
    float* emb   = (float*)(ws + 196608 + 6291456);    // 12288*64*4  = 3145728 B
    float* out   = (float*)d_out;

    hipLaunchKernelGGL(prep_kernel, dim3(384), dim3(256), 0, stream, W_ih, W_hh, wfrag);
    hipLaunchKernelGGL(gru_agg_kernel, dim3(6144), dim3(512), 0, stream,
                       ngh_id, e_idx, ngh_ts, hidden, e_feat, basis, phase, cut_time,
                       wfrag, b_ih, b_hh, agg);
    hipLaunchKernelGGL(emb_kernel, dim3(768), dim3(256), 0, stream,
                       src_ids, tgt_ids, bad_ids, n_feat, W_out, b_out, agg, emb);
    hipLaunchKernelGGL(merge_kernel, dim3(256), dim3(256), 0, stream,
                       emb, fc1_w, fc1_b, fc2_w, fc2_b, out);
}